// Round 7
// baseline (852.285 us; speedup 1.0000x reference)
//
#include <hip/hip_runtime.h>

#define Bdim 256
#define Tdim 512
#define Kdim 128
#define CHUNK 8

typedef float v2f __attribute__((ext_vector_type(2)));

// Compiler-only fence: forbids reordering of LDS ops across it (runtime-free).
// Needed because lane X's read of abuf depends on lane Y's write — a
// cross-lane dependency the per-thread memory model can't see. HW executes
// the wave's DS ops in issue order (in-order LDS pipe), so program order is
// all we need to enforce.
#define WFENCE() do { asm volatile("" ::: "memory"); \
                      __builtin_amdgcn_wave_barrier(); } while (0)

// One block = one WAVE = one sequence. Lane l owns output columns {2l,2l+1}
// and the full E-columns e2[128] (float2 = 256 VGPRs, forced resident by
// amdgpu_waves_per_eu(1,1) — rounds 3-6 showed launch_bounds alone lets the
// allocator remat the fragment into the step loop: VGPR_Count 92/48/60/44/28,
// always below fragment size, step pinned ~930cy).
// Per step: 32 uniform ds_read_b128 broadcasts of A + 128 v_pk_fma_f32,
// sum is lane-local (NO cross-lane reduce, NO s_barrier — intra-wave LDS
// ordering only). alpha in LINEAR space, renormalized by A[0] each step;
// log/exp run under the FMA issue window (p0 = chunk 0 of the reads).
__global__ __launch_bounds__(64) __attribute__((amdgpu_waves_per_eu(1, 1)))
void crf_nll_kernel(
    const float* __restrict__ logits,   // B*T*K fp32
    const int*   __restrict__ labels,   // B*T   int32
    const int*   __restrict__ seq_lens, // B     int32
    const float* __restrict__ trans,    // K*K   fp32
    float* __restrict__ out)            // 1     fp32 (pre-zeroed)
{
    const int b    = blockIdx.x;
    const int lane = threadIdx.x;       // 0..63
    const int j0   = lane * 2;          // this lane's columns j0, j0+1
    const int L    = seq_lens[b];       // 1..T (uniform per block)

    __shared__ float abuf[Kdim];        // the A/B vector, single buffer

    const int*   lab_b   = labels + (size_t)b * Tdim;
    const float* logit_b = logits + (size_t)b * Tdim * Kdim;

    // ---- E columns (j0, j0+1), all 128 rows: e2[i] = exp(trans[i][j0:j0+2])
    v2f e2[Kdim];
    #pragma unroll
    for (int i = 0; i < Kdim; ++i) {
        const float2 tr = *(const float2*)&trans[(size_t)i * Kdim + j0];
        v2f v; v.x = __expf(tr.x); v.y = __expf(tr.y);
        e2[i] = v;
    }

    // ---- gold-path score: 8 timesteps per lane ----
    float s = 0.f;
    #pragma unroll
    for (int t0 = 0; t0 < Tdim; t0 += 64) {
        const int t = t0 + lane;
        if (t < L) {
            const int lb = lab_b[t];
            s += logit_b[(size_t)t * Kdim + lb];
            if (t >= 1) s += trans[(size_t)lab_b[t - 1] * Kdim + lb];
        }
    }
    #pragma unroll
    for (int o = 32; o > 0; o >>= 1) s += __shfl_down(s, o, 64);
    const float score = s;              // valid in lane 0

    // ---- init B_0 = exp(l_0), linear space ----
    {
        const float2 l0 = *(const float2*)&logit_b[j0];
        float2 b0; b0.x = __expf(l0.x); b0.y = __expf(l0.y);
        *(float2*)&abuf[j0] = b0;
    }
    float off = 0.f;
    WFENCE();                           // init write before step-1 reads

    // ---- prefetch first logit chunk (t = 1..8), this lane's columns ----
    v2f curl[CHUNK], nxtl[CHUNK];
    #pragma unroll
    for (int u = 0; u < CHUNK; ++u) {
        const int tt = 1 + u;
        curl[u] = (tt < Tdim) ? *(const v2f*)&logit_b[(size_t)tt * Kdim + j0]
                              : (v2f){0.f, 0.f};
    }

    // ---- forward recursion: barrier-free, wave-synchronous ----
    for (int tb = 1; tb < L; tb += CHUNK) {
        #pragma unroll
        for (int u = 0; u < CHUNK; ++u) {      // prefetch next chunk
            const int tt = tb + CHUNK + u;
            nxtl[u] = (tt < Tdim) ? *(const v2f*)&logit_b[(size_t)tt * Kdim + j0]
                                  : (v2f){0.f, 0.f};
        }
        #pragma unroll
        for (int u = 0; u < CHUNK; ++u) {
            const int t = tb + u;
            if (t < L) {                       // uniform per block
                const float4* a4 = (const float4*)abuf;
                v2f acc0 = {0.f, 0.f}, acc1 = {0.f, 0.f};
                v2f acc2 = {0.f, 0.f}, acc3 = {0.f, 0.f};
                float p0 = 1.f;
                #pragma unroll
                for (int k = 0; k < Kdim / 4; ++k) {
                    const float4 p = a4[k];    // uniform addr -> broadcast
                    if (k == 0) p0 = p.x;
                    acc0 = __builtin_elementwise_fma((v2f){p.x, p.x}, e2[4*k+0], acc0);
                    acc1 = __builtin_elementwise_fma((v2f){p.y, p.y}, e2[4*k+1], acc1);
                    acc2 = __builtin_elementwise_fma((v2f){p.z, p.z}, e2[4*k+2], acc2);
                    acc3 = __builtin_elementwise_fma((v2f){p.w, p.w}, e2[4*k+3], acc3);
                }
                // renormalizer path runs under the FMA issue window
                const float lp0 = __logf(p0);
                v2f sc;
                sc.x = __expf(curl[u].x - lp0);
                sc.y = __expf(curl[u].y - lp0);
                off += lp0;
                const v2f an = ((acc0 + acc1) + (acc2 + acc3)) * sc;
                WFENCE();                      // all reads before the write
                *(v2f*)&abuf[j0] = an;
                WFENCE();                      // write before next step's reads
            }
        }
        #pragma unroll
        for (int u = 0; u < CHUNK; ++u) curl[u] = nxtl[u];
    }

    // ---- log_z = off + log(sum_j B[j]); nll = log_z - score ----
    const float2 fb = *(const float2*)&abuf[j0];
    float as = fb.x + fb.y;
    #pragma unroll
    for (int o = 32; o > 0; o >>= 1) as += __shfl_down(as, o, 64);
    if (lane == 0) {
        const float logz = off + __logf(as);
        atomicAdd(out, logz - score);
    }
}

extern "C" void kernel_launch(void* const* d_in, const int* in_sizes, int n_in,
                              void* d_out, int out_size, void* d_ws, size_t ws_size,
                              hipStream_t stream) {
    const float* logits   = (const float*)d_in[0];
    const int*   labels   = (const int*)d_in[1];
    const int*   seq_lens = (const int*)d_in[2];
    const float* trans    = (const float*)d_in[3];
    float* out = (float*)d_out;

    (void)hipMemsetAsync(out, 0, sizeof(float), stream);
    crf_nll_kernel<<<dim3(Bdim), dim3(64), 0, stream>>>(
        logits, labels, seq_lens, trans, out);
}

// Round 8
// 247.332 us; speedup vs baseline: 3.4459x; 3.4459x over previous
//
#include <hip/hip_runtime.h>

#define Bdim 256
#define Tdim 512
#define Kdim 128
#define NT   256   // thread (j4 = tid>>3, g = tid&7): 4 columns x 16-row slice
#define CHUNK 8

typedef float v2f __attribute__((ext_vector_type(2)));

// Raw barrier: drain LDS ops only (NOT vmcnt) so global prefetches stay in
// flight across steps; then s_barrier. "memory" stops compiler reordering.
#define BAR() asm volatile("s_waitcnt lgkmcnt(0)\n\ts_barrier" ::: "memory")

// DPP butterfly add. 0xB1 = quad_perm [1,0,3,2] (xor 1); 0x4E = [2,3,0,1]
// (xor 2); 0x141 = row_half_mirror (lane i <-> 7-i within each 8-lane half-
// row: after xor1+xor2 it adds the other quad's total -> full 8-lane sum).
template <int CTRL>
__device__ __forceinline__ float dpp_add(float v) {
    int r = __builtin_amdgcn_update_dpp(0, __float_as_int(v), CTRL, 0xF, 0xF, true);
    return v + __int_as_float(r);
}

// One block per batch element, 256 threads (4 waves, 1 per SIMD).
// Thread (j4, g) accumulates columns {4j4..4j4+3} over rows [16g, 16g+16):
// 64-float E fragment held as 32 v2f. amdgpu_waves_per_eu(1,1) forces full
// register allocation (round 7 proved this lever; rounds 0-6 showed that
// without it the allocator remats the fragment into the step loop —
// VGPR_Count 92/48/60/44/28, always below fragment size, ~930cy/step).
// Live set ~120 regs < 256 arch-VGPR cap (round 7's 300-reg layout spilled).
// Per step: 4 ds_read_b128 (bank-staggered), 32 v_pk_fma_f32, 12 DPP adds,
// select, 1 mul, masked ds_write, lgkm-only barrier. alpha in LINEAR space;
// renormalize by A[0] every 4th step only (growth <= ~1e16 per 4 steps,
// fp32 max 3.4e38) so exp(logit) precomputes per chunk off the serial path.
__global__ __launch_bounds__(NT, 1) __attribute__((amdgpu_waves_per_eu(1, 1)))
void crf_nll_kernel(
    const float* __restrict__ logits,   // B*T*K fp32
    const int*   __restrict__ labels,   // B*T   int32
    const int*   __restrict__ seq_lens, // B     int32
    const float* __restrict__ trans,    // K*K   fp32
    float* __restrict__ out)            // 1     fp32 (pre-zeroed)
{
    const int b   = blockIdx.x;
    const int tid = threadIdx.x;
    const int j4  = tid >> 3;           // column set 0..31 (cols 4j4..4j4+3)
    const int g   = tid & 7;            // row-slice group 0..7
    const int cj  = 4 * j4 + (g & 3);   // this lane's write/logit column
    const int L   = seq_lens[b];        // 1..T (uniform per block)

    __shared__ float pbuf[2][Kdim];
    __shared__ float sred[NT / 64];

    const int*   lab_b   = labels + (size_t)b * Tdim;
    const float* logit_b = logits + (size_t)b * Tdim * Kdim;

    // ---- E fragment (16 rows x 4 cols) as v2f pairs. Read-inst ii accesses
    // float4 idx = 4g + ((ii+g)&3): per instruction the 8 distinct addresses
    // alias each bank-quad exactly 2-way (free, m136).
    // e01[ii][ci] = exp(trans[row][4j4+0..1]), e23 = cols 4j4+2..3,
    // row = 16g + 4*((ii+g)&3) + ci.
    v2f e01[4][4], e23[4][4];
    #pragma unroll
    for (int ii = 0; ii < 4; ++ii) {
        const int row0 = 16 * g + (((ii + g) & 3) << 2);
        #pragma unroll
        for (int ci = 0; ci < 4; ++ci) {
            const float4 tr =
                *(const float4*)&trans[(size_t)(row0 + ci) * Kdim + 4 * j4];
            e01[ii][ci] = (v2f){__expf(tr.x), __expf(tr.y)};
            e23[ii][ci] = (v2f){__expf(tr.z), __expf(tr.w)};
        }
    }

    // ---- gold-path score: 2 timesteps per thread ----
    float s = 0.f;
    #pragma unroll
    for (int t0 = 0; t0 < Tdim; t0 += NT) {
        const int t = t0 + tid;
        if (t < L) {
            const int lb = lab_b[t];
            s += logit_b[(size_t)t * Kdim + lb];
            if (t >= 1) s += trans[(size_t)lab_b[t - 1] * Kdim + lb];
        }
    }
    #pragma unroll
    for (int o = 32; o > 0; o >>= 1) s += __shfl_down(s, o, 64);
    if ((tid & 63) == 0) sred[tid >> 6] = s;

    // ---- init alpha (t = 0), linear space; g<4 lanes own a column ----
    if (g < 4) pbuf[0][cj] = __expf(logit_b[cj]);
    float off = 0.f;
    int cb = 0;
    __syncthreads();

    float score = 0.f;
    if (tid == 0) {
        #pragma unroll
        for (int w = 0; w < NT / 64; ++w) score += sred[w];
    }

    // ---- prefetch first logit chunk (t = 1..8), this lane's column ----
    float curl[CHUNK], nxtl[CHUNK], ex[CHUNK];
    #pragma unroll
    for (int u = 0; u < CHUNK; ++u) {
        const int tt = 1 + u;
        curl[u] = (tt < Tdim) ? logit_b[(size_t)tt * Kdim + cj] : 0.f;
    }

    // ---- forward recursion ----
    for (int tb = 1; tb < L; tb += CHUNK) {
        #pragma unroll
        for (int u = 0; u < CHUNK; ++u) {    // prefetch next chunk
            const int tt = tb + CHUNK + u;
            nxtl[u] = (tt < Tdim) ? logit_b[(size_t)tt * Kdim + cj] : 0.f;
        }
        #pragma unroll
        for (int u = 0; u < CHUNK; ++u)      // exp(logit) off the serial path
            ex[u] = __expf(curl[u]);
        #pragma unroll
        for (int u = 0; u < CHUNK; ++u) {
            const int t = tb + u;
            if (t < L) {                     // uniform per block
                const float4* a4 = (const float4*)pbuf[cb];
                float p0 = 1.f;
                if ((u & 3) == 3) p0 = pbuf[cb][0];   // renorm steps only
                v2f A0 = {0.f, 0.f}, A1 = {0.f, 0.f};
                v2f B0 = {0.f, 0.f}, B1 = {0.f, 0.f};
                #pragma unroll
                for (int ii = 0; ii < 4; ++ii) {
                    const float4 p = a4[(g << 2) + ((ii + g) & 3)];
                    A0 = __builtin_elementwise_fma((v2f){p.x, p.x}, e01[ii][0], A0);
                    A1 = __builtin_elementwise_fma((v2f){p.x, p.x}, e23[ii][0], A1);
                    B0 = __builtin_elementwise_fma((v2f){p.y, p.y}, e01[ii][1], B0);
                    B1 = __builtin_elementwise_fma((v2f){p.y, p.y}, e23[ii][1], B1);
                    A0 = __builtin_elementwise_fma((v2f){p.z, p.z}, e01[ii][2], A0);
                    A1 = __builtin_elementwise_fma((v2f){p.z, p.z}, e23[ii][2], A1);
                    B0 = __builtin_elementwise_fma((v2f){p.w, p.w}, e01[ii][3], B0);
                    B1 = __builtin_elementwise_fma((v2f){p.w, p.w}, e23[ii][3], B1);
                }
                const v2f s01 = A0 + B0;     // cols (4j4+0, 4j4+1)
                const v2f s23 = A1 + B1;     // cols (4j4+2, 4j4+3)
                float c0 = s01.x, c1 = s01.y, c2 = s23.x, c3 = s23.y;
                // 8-lane reduce per column, pure DPP
                c0 = dpp_add<0xB1>(c0); c0 = dpp_add<0x4E>(c0); c0 = dpp_add<0x141>(c0);
                c1 = dpp_add<0xB1>(c1); c1 = dpp_add<0x4E>(c1); c1 = dpp_add<0x141>(c1);
                c2 = dpp_add<0xB1>(c2); c2 = dpp_add<0x4E>(c2); c2 = dpp_add<0x141>(c2);
                c3 = dpp_add<0xB1>(c3); c3 = dpp_add<0x4E>(c3); c3 = dpp_add<0x141>(c3);
                // select this lane's column (c = g&3)
                float sel  = (g & 1) ? c1 : c0;
                float selh = (g & 1) ? c3 : c2;
                sel = (g & 2) ? selh : sel;
                float anew = sel * ex[u];
                if ((u & 3) == 3) {          // renormalize by A[0]
                    const float lp0 = __logf(p0);
                    anew *= __expf(-lp0);
                    off  += lp0;
                }
                if (g < 4) pbuf[cb ^ 1][cj] = anew;
                cb ^= 1;
                BAR();                       // lgkm-only barrier per step
            }
        }
        #pragma unroll
        for (int u = 0; u < CHUNK; ++u) curl[u] = nxtl[u];
    }

    // ---- log_z = off + log(sum_j A[j]); nll = log_z - score ----
    __syncthreads();
    float as = (tid < Kdim) ? pbuf[cb][tid] : 0.f;
    #pragma unroll
    for (int o = 32; o > 0; o >>= 1) as += __shfl_down(as, o, 64);
    __syncthreads();
    if ((tid & 63) == 0) sred[tid >> 6] = as;
    __syncthreads();
    if (tid == 0) {
        float tot = 0.f;
        #pragma unroll
        for (int w = 0; w < NT / 64; ++w) tot += sred[w];
        const float logz = off + __logf(tot);
        atomicAdd(out, logz - score);
    }
}

extern "C" void kernel_launch(void* const* d_in, const int* in_sizes, int n_in,
                              void* d_out, int out_size, void* d_ws, size_t ws_size,
                              hipStream_t stream) {
    const float* logits   = (const float*)d_in[0];
    const int*   labels   = (const int*)d_in[1];
    const int*   seq_lens = (const int*)d_in[2];
    const float* trans    = (const float*)d_in[3];
    float* out = (float*)d_out;

    (void)hipMemsetAsync(out, 0, sizeof(float), stream);
    crf_nll_kernel<<<dim3(Bdim), dim3(NT), 0, stream>>>(
        logits, labels, seq_lens, trans, out);
}